// Round 5
// baseline (490.898 us; speedup 1.0000x reference)
//
#include <hip/hip_runtime.h>
#include <hip/hip_bf16.h>

#define N_NODES 50000
#define N_EDGES 1600000
#define D 512

typedef __attribute__((ext_vector_type(8))) short short8;
typedef __attribute__((ext_vector_type(4))) float f32x4;
typedef __attribute__((ext_vector_type(2))) float f32x2;
typedef __attribute__((ext_vector_type(8))) unsigned short u16x8;

__device__ __forceinline__ void async_copy16(const void* g, void* l) {
    __builtin_amdgcn_global_load_lds(
        (const __attribute__((address_space(1))) unsigned int*)g,
        (__attribute__((address_space(3))) unsigned int*)l, 16, 0, 0);
}

// --- fused prep: [0,12500) cvt X->bf16 | [12500,13524) W transpose+cast | [13524,13720) rowptr ---
#define CVT_BLOCKS 12500
#define WT_BLOCKS  1024
#define RP_BLOCKS  196
__global__ __launch_bounds__(256) void prep_kernel(const float* __restrict__ X,
                                                   unsigned short* __restrict__ Xb,
                                                   const float* __restrict__ W,
                                                   unsigned short* __restrict__ Wt,
                                                   const int* __restrict__ rows,
                                                   int* __restrict__ row_start) {
    const int b = blockIdx.x;
    if (b < CVT_BLOCKS) {
        size_t idx = (size_t)(b * 256 + threadIdx.x) * 8;
        f32x4 v0 = *(const f32x4*)(X + idx);
        f32x4 v1 = *(const f32x4*)(X + idx + 4);
        u16x8 u;
#pragma unroll
        for (int k = 0; k < 4; ++k) {
            u[k]     = __bfloat16_as_ushort(__float2bfloat16(v0[k]));
            u[k + 4] = __bfloat16_as_ushort(__float2bfloat16(v1[k]));
        }
        *(u16x8*)(Xb + idx) = u;
    } else if (b < CVT_BLOCKS + WT_BLOCKS) {
        int idx = (b - CVT_BLOCKS) * 256 + threadIdx.x;   // over 512*512
        int k = idx >> 9;
        int n = idx & 511;
        Wt[n * D + k] = __bfloat16_as_ushort(__float2bfloat16(W[k * D + n]));
    } else {
        int r = (b - CVT_BLOCKS - WT_BLOCKS) * 256 + threadIdx.x;
        if (r > N_NODES) return;
        int lo = 0, hi = N_EDGES;
        while (lo < hi) {
            int mid = (lo + hi) >> 1;
            if (rows[mid] < r) lo = mid + 1; else hi = mid;
        }
        row_start[r] = lo;
    }
}

// --- support = bf16(Xb @ Wt^T) — UNCHANGED from round 2/4 (attribution control) ---
__global__ __launch_bounds__(256) void gemm_kernel(const unsigned short* __restrict__ Xb,
                                                   const unsigned short* __restrict__ Wt,
                                                   __hip_bfloat16* __restrict__ support) {
    __shared__ unsigned short As[128 * 32];
    __shared__ unsigned short Bs[128 * 32];

    const int t = threadIdx.x;
    const int lane = t & 63;
    const int wave = t >> 6;
    const int wm = (wave & 1) * 64;
    const int wn = (wave >> 1) * 64;
    const int m0 = blockIdx.x * 128;
    const int n0 = blockIdx.y * 128;
    const int l15 = lane & 15;
    const int quad = lane >> 4;

    f32x4 acc[4][4];
#pragma unroll
    for (int i = 0; i < 4; ++i)
#pragma unroll
        for (int j = 0; j < 4; ++j) acc[i][j] = (f32x4)(0.0f);

    const int srow = t >> 2;
    const int skb = (t & 3) * 8;
    int gra = m0 + srow;        if (gra > N_NODES - 1) gra = N_NODES - 1;
    int grb = m0 + 64 + srow;   if (grb > N_NODES - 1) grb = N_NODES - 1;
    const size_t aoff0 = (size_t)gra * D + skb;
    const size_t aoff1 = (size_t)grb * D + skb;
    const size_t boff0 = (size_t)(n0 + srow) * D + skb;
    const size_t boff1 = (size_t)(n0 + 64 + srow) * D + skb;
    unsigned short* lA = As + t * 8;
    unsigned short* lB = Bs + t * 8;

    for (int kt = 0; kt < D / 32; ++kt) {
        const int k0 = kt * 32;
        async_copy16(Xb + aoff0 + k0, lA);
        async_copy16(Xb + aoff1 + k0, lA + 2048);
        async_copy16(Wt + boff0 + k0, lB);
        async_copy16(Wt + boff1 + k0, lB + 2048);
        __syncthreads();

        short8 af[4], bf[4];
#pragma unroll
        for (int i = 0; i < 4; ++i) af[i] = *(const short8*)(As + (wm + i * 16 + l15) * 32 + quad * 8);
#pragma unroll
        for (int j = 0; j < 4; ++j) bf[j] = *(const short8*)(Bs + (wn + j * 16 + l15) * 32 + quad * 8);
#pragma unroll
        for (int i = 0; i < 4; ++i)
#pragma unroll
            for (int j = 0; j < 4; ++j)
                acc[i][j] = __builtin_amdgcn_mfma_f32_16x16x32_bf16(af[i], bf[j], acc[i][j], 0, 0, 0);
        __syncthreads();
    }

#pragma unroll
    for (int i = 0; i < 4; ++i) {
        int grow = m0 + wm + i * 16 + quad * 4;
#pragma unroll
        for (int j = 0; j < 4; ++j) {
            int gc = n0 + wn + j * 16 + l15;
#pragma unroll
            for (int rr = 0; rr < 4; ++rr) {
                int gr = grow + rr;
                if (gr < N_NODES)
                    support[(size_t)gr * D + gc] = __float2bfloat16(acc[i][j][rr]);
            }
        }
    }
}

// --- SpMM: identical inner loop to r4, but row-offset parameterized (8-way split) ---
__global__ __launch_bounds__(256) void spmm_kernel(const unsigned short* __restrict__ support,
                                                   const int* __restrict__ cols,
                                                   const float* __restrict__ vals,
                                                   const int* __restrict__ row_start,
                                                   float* __restrict__ out,
                                                   int r0) {
    const int r = r0 + blockIdx.x;
    if (r >= N_NODES) return;
    const int t = threadIdx.x;           // thread owns cols 2t, 2t+1
    const int s = row_start[r];
    const int e = row_start[r + 1];
    const size_t co = 2 * t;

    float ax = 0.f, ay = 0.f;
    int i = s;
    for (; i + 8 <= e; i += 8) {
        int c[8]; float v[8]; unsigned int h[8];
#pragma unroll
        for (int k = 0; k < 8; ++k) { c[k] = cols[i + k]; v[k] = vals[i + k]; }
#pragma unroll
        for (int k = 0; k < 8; ++k)
            h[k] = *(const unsigned int*)(support + (size_t)c[k] * D + co);
#pragma unroll
        for (int k = 0; k < 8; ++k) {
            ax += v[k] * __uint_as_float(h[k] << 16);
            ay += v[k] * __uint_as_float(h[k] & 0xffff0000u);
        }
    }
    for (; i < e; ++i) {
        int c = cols[i];
        float v = vals[i];
        unsigned int h = *(const unsigned int*)(support + (size_t)c * D + co);
        ax += v * __uint_as_float(h << 16);
        ay += v * __uint_as_float(h & 0xffff0000u);
    }
    f32x2 o; o[0] = ax; o[1] = ay;
    __builtin_nontemporal_store(o, (f32x2*)(out + (size_t)r * D + co));
}

extern "C" void kernel_launch(void* const* d_in, const int* in_sizes, int n_in,
                              void* d_out, int out_size, void* d_ws, size_t ws_size,
                              hipStream_t stream) {
    (void)in_sizes; (void)n_in; (void)out_size; (void)ws_size;
    const float* X    = (const float*)d_in[0];
    const float* W    = (const float*)d_in[1];
    const int* rows   = (const int*)d_in[2];
    const int* cols   = (const int*)d_in[3];
    const float* vals = (const float*)d_in[4];
    float* out = (float*)d_out;

    unsigned short* support = (unsigned short*)d_ws;            // 51.2 MB
    unsigned short* Wt      = support + (size_t)N_NODES * D;    // 0.5 MB
    int* row_start          = (int*)(Wt + (size_t)D * D);       // 200 KB
    unsigned short* Xb = (unsigned short*)d_out;                // scratch in d_out, overwritten by spmm

    prep_kernel<<<CVT_BLOCKS + WT_BLOCKS + RP_BLOCKS, 256, 0, stream>>>(
        X, Xb, W, Wt, rows, row_start);

    dim3 gg((N_NODES + 127) / 128, D / 128);
    gemm_kernel<<<gg, 256, 0, stream>>>(Xb, Wt, (__hip_bfloat16*)support);

    // 8-way split: attribution — slowest dispatch class surfaces in rocprof top-5
    for (int p = 0; p < 8; ++p)
        spmm_kernel<<<6250, 256, 0, stream>>>(support, cols, vals, row_start, out, p * 6250);
}